// Round 8
// baseline (389.458 us; speedup 1.0000x reference)
//
#include <hip/hip_runtime.h>
#include <hip/hip_cooperative_groups.h>

// ---- output layout (floats) ----
#define LOSS_OFF  8388608
#define IDX_OFF   8388609
#define NCS_OFF   8454145
#define EMAW_OFF  8454657
#define EMB_OFF   8520193

typedef __attribute__((ext_vector_type(8))) short short8;
typedef __attribute__((ext_vector_type(4))) float f32x4;

#define LOG2E 1.4426950408889634f
#define N2L2E -2.8853900817779268f   // -2*log2(e)
#define LN2   0.6931471805599453f
#define NSPLIT 32                     // scatter row-splits

__device__ __forceinline__ unsigned short bf16r(float x) {
  unsigned u = __float_as_uint(x);
  u += 0x7fff + ((u >> 16) & 1);
  return (unsigned short)(u >> 16);
}
__device__ __forceinline__ float bf16tof(unsigned short h) {
  return __uint_as_float(((unsigned)h) << 16);
}

// codebook prep: bf16 hi/lo split + log2e*||e_k||^2. grid 256 (2 codes/block)
__global__ __launch_bounds__(256) void prep_kernel(const float* __restrict__ emb,
    unsigned short* __restrict__ ehig, unsigned short* __restrict__ elog,
    float* __restrict__ eeg)
{
  __shared__ float r1[256];
  const int t = threadIdx.x;
  const int k = blockIdx.x * 2 + (t >> 7);
  const int c = t & 127;
  float x = emb[k * 128 + c];
  unsigned short hh = bf16r(x);
  ehig[k * 128 + c] = hh;
  elog[k * 128 + c] = bf16r(x - bf16tof(hh));
  r1[t] = x * x;
  __syncthreads();
  #pragma unroll
  for (int off = 64; off; off >>= 1) {
    if ((t & 127) < off) r1[t] += r1[t + off];
    __syncthreads();
  }
  if ((t & 127) == 0) eeg[k] = LOG2E * r1[t];
}

// distances via split-bf16 MFMA + argmin + base-2 fused-entropy softmax.
// (unchanged from round 7 — 59 us, VGPR 64, no spill)
__global__ __attribute__((amdgpu_flat_work_group_size(256, 256),
                          amdgpu_waves_per_eu(2, 4)))
void dist_kernel(const float* __restrict__ inputs,
                 const unsigned short* __restrict__ ehig,
                 const unsigned short* __restrict__ elog,
                 const float* __restrict__ eeg,
                 float* __restrict__ out, float* __restrict__ idxws,
                 float* __restrict__ sums)
{
  __shared__ __align__(16) short esm[2][2][32 * 136];  // [buf][hi/lo] 34 KB
  __shared__ float eeL[512];
  __shared__ float xxs[64];
  __shared__ float red[8];
  float* xs = (float*)&esm[0][0][0];          // [32][132] fp32, transient alias

  const int t = threadIdx.x, lane = t & 63, wave = t >> 6;
  const int n0 = blockIdx.x * 64;
  const int b = n0 >> 15, s0 = n0 & 32767;
  const int col = lane & 15, quad = lane >> 4;
  const int kk = t >> 3, c0s = (t & 7) * 16;  // staging coords

  eeL[t] = eeg[t]; eeL[256 + t] = eeg[256 + t];

  short8 ahi[4], alo[4];
  for (int r4 = 0; r4 < 2; ++r4) {
    __syncthreads();
    {
      const int rr = t & 31, cc = (t >> 5) * 16;
      const float* src = inputs + (size_t)b * 128 * 32768 + s0 + r4 * 32 + rr;
      #pragma unroll
      for (int i = 0; i < 16; ++i)
        xs[rr * 132 + cc + i] = src[(size_t)(cc + i) * 32768];
    }
    __syncthreads();
    if ((wave >> 1) == r4) {
      float xacc = 0.f;
      const float* xr = &xs[((wave & 1) * 16 + col) * 132 + quad * 8];
      #pragma unroll
      for (int q = 0; q < 4; ++q) {
        float v[8];
        *(float4*)&v[0] = *(const float4*)(xr + q * 32);
        *(float4*)&v[4] = *(const float4*)(xr + q * 32 + 4);
        short8 h8, l8;
        #pragma unroll
        for (int j = 0; j < 8; ++j) {
          unsigned short hh = bf16r(v[j]);
          h8[j] = (short)hh;
          l8[j] = (short)bf16r(v[j] - bf16tof(hh));
          xacc += v[j] * v[j];
        }
        ahi[q] = h8; alo[q] = l8;
      }
      xacc += __shfl_xor(xacc, 16);
      xacc += __shfl_xor(xacc, 32);
      if (quad == 0) xxs[wave * 16 + col] = xacc;
    }
  }
  __syncthreads();

  uint4 ph0, ph1, pl0, pl1;
  {
    const size_t go = (size_t)kk * 128 + c0s;
    ph0 = ((const uint4*)(ehig + go))[0]; ph1 = ((const uint4*)(ehig + go))[1];
    pl0 = ((const uint4*)(elog + go))[0]; pl1 = ((const uint4*)(elog + go))[1];
  }
  *(uint4*)&esm[0][0][kk * 136 + c0s] = ph0;
  *(uint4*)&esm[0][0][kk * 136 + c0s + 8] = ph1;
  *(uint4*)&esm[0][1][kk * 136 + c0s] = pl0;
  *(uint4*)&esm[0][1][kk * 136 + c0s + 8] = pl1;
  {
    const size_t go = (size_t)(32 + kk) * 128 + c0s;
    ph0 = ((const uint4*)(ehig + go))[0]; ph1 = ((const uint4*)(ehig + go))[1];
    pl0 = ((const uint4*)(elog + go))[0]; pl1 = ((const uint4*)(elog + go))[1];
  }

  float mS[4], sS[4], tS[4]; int kS[4];
  #pragma unroll
  for (int i = 0; i < 4; ++i) { mS[i] = 1e30f; sS[i] = 0.f; tS[i] = 0.f; kS[i] = 0; }

  for (int st = 0; st < 16; ++st) {
    const int pb = st & 1;
    __syncthreads();
    #pragma unroll
    for (int kt = 0; kt < 2; ++kt) {
      f32x4 ac = {0.f, 0.f, 0.f, 0.f};
      const int boff = (kt * 16 + col) * 136 + quad * 8;
      #pragma unroll
      for (int q = 0; q < 4; ++q) {
        short8 bh = *(const short8*)&esm[pb][0][boff + q * 32];
        short8 bl = *(const short8*)&esm[pb][1][boff + q * 32];
        ac = __builtin_amdgcn_mfma_f32_16x16x32_bf16(alo[q], bh, ac, 0, 0, 0);
        ac = __builtin_amdgcn_mfma_f32_16x16x32_bf16(ahi[q], bl, ac, 0, 0, 0);
        ac = __builtin_amdgcn_mfma_f32_16x16x32_bf16(ahi[q], bh, ac, 0, 0, 0);
      }
      const int code = st * 32 + kt * 16 + col;
      const float eec2 = eeL[code];
      #pragma unroll
      for (int si = 0; si < 4; ++si) {
        float d  = fmaf(ac[si], N2L2E, eec2);
        float mo = mS[si];
        float mn = fminf(mo, d);
        float mx = fmaxf(mo, d);
        float E  = __builtin_amdgcn_exp2f(mn - mx);
        bool nw  = d < mo;
        float f  = nw ? E : 1.f;
        float e2 = nw ? 1.f : E;
        tS[si] = (tS[si] + (mn - mo) * sS[si]) * f + (mn - d) * e2;
        sS[si] = sS[si] * f + e2;
        kS[si] = nw ? code : kS[si];
        mS[si] = mn;
      }
    }
    if (st < 15) {
      const int nb = pb ^ 1;
      *(uint4*)&esm[nb][0][kk * 136 + c0s] = ph0;
      *(uint4*)&esm[nb][0][kk * 136 + c0s + 8] = ph1;
      *(uint4*)&esm[nb][1][kk * 136 + c0s] = pl0;
      *(uint4*)&esm[nb][1][kk * 136 + c0s + 8] = pl1;
      if (st < 14) {
        const size_t go = (size_t)((st + 2) * 32 + kk) * 128 + c0s;
        ph0 = ((const uint4*)(ehig + go))[0]; ph1 = ((const uint4*)(ehig + go))[1];
        pl0 = ((const uint4*)(elog + go))[0]; pl1 = ((const uint4*)(elog + go))[1];
      }
    }
  }

  #pragma unroll
  for (int off = 1; off <= 8; off <<= 1) {
    #pragma unroll
    for (int si = 0; si < 4; ++si) {
      float m2 = __shfl_xor(mS[si], off);
      float S2 = __shfl_xor(sS[si], off);
      float T2 = __shfl_xor(tS[si], off);
      int   k2 = __shfl_xor(kS[si], off);
      float mo = mS[si];
      float mn = fminf(mo, m2);
      float f1 = __builtin_amdgcn_exp2f(mn - mo);
      float f2 = __builtin_amdgcn_exp2f(mn - m2);
      tS[si] = (tS[si] + (mn - mo) * sS[si]) * f1 + (T2 + (mn - m2) * S2) * f2;
      sS[si] = sS[si] * f1 + S2 * f2;
      if (m2 < mo || (m2 == mo && k2 < kS[si])) kS[si] = k2;
      mS[si] = mn;
    }
  }

  float cacc = 0.f, eacc = 0.f;
  if (col == 0) {
    #pragma unroll
    for (int si = 0; si < 4; ++si) {
      int row = wave * 16 + quad * 4 + si;
      int rn = n0 + row;
      float fk = (float)kS[si];
      out[IDX_OFF + rn] = fk;
      idxws[rn] = fk;
      cacc += xxs[row] + mS[si] * LN2;
      eacc += LN2 * (tS[si] / sS[si] - __builtin_amdgcn_logf(sS[si]));
    }
  }
  cacc += __shfl_xor(cacc, 16); cacc += __shfl_xor(cacc, 32);
  eacc += __shfl_xor(eacc, 16); eacc += __shfl_xor(eacc, 32);
  if (lane == 0) { red[wave] = cacc; red[4 + wave] = eacc; }
  __syncthreads();
  if (t == 0) {
    unsafeAtomicAdd(&sums[0], red[0] + red[1] + red[2] + red[3]);
    unsafeAtomicAdd(&sums[1], red[4] + red[5] + red[6] + red[7]);
  }
}

// ---------- fused tail: scatter || gather, grid.sync, fin ----------
// grid 768 x 256 (3 blocks/CU needed; 32 KB LDS -> 4/CU fits).
// blocks 0..511: dw scatter (partials -> ws). blocks 512..767: quantized gather.
// after grid sync: blocks 0..255 finalize (counts, smoothed, loss, EMA, emb).
__global__ __launch_bounds__(256, 4) void coop_kernel(
    const float* __restrict__ inputs, const float* __restrict__ idxws,
    float* __restrict__ partial, float* __restrict__ cpart,
    const float* __restrict__ ecs, const float* __restrict__ emaw,
    const float* __restrict__ sums, const float* __restrict__ emb,
    float* __restrict__ out)
{
  __shared__ float sh[8192];   // 32 KB union: scatter acc+cnts / gather eq / fin cn
  const int t = threadIdx.x;
  const int bid = blockIdx.x;
  cooperative_groups::grid_group grid = cooperative_groups::this_grid();

  if (bid < 512) {
    // ---- scatter: (row-split s, 8-channel slice ccB) ----
    float* acc  = sh;           // 512*9
    float* cnts = sh + 4608;    // 512
    const int s = bid >> 4, ccB = bid & 15;
    const int R = 65536 / NSPLIT;
    for (int m = t; m < 4608; m += 256) acc[m] = 0.f;
    if (ccB == 0) for (int m = t; m < 512; m += 256) cnts[m] = 0.f;
    __syncthreads();
    const int l = t & 63, cg = t >> 6;
    for (int it = 0; it < R / 256; ++it) {
      int n = s * R + it * 256;
      int bb = n >> 15;
      int sp = (n & 32767) + 4 * l;
      float4 i4 = *(const float4*)(idxws + n + 4 * l);
      int k0 = (int)i4.x, k1 = (int)i4.y, k2 = (int)i4.z, k3 = (int)i4.w;
      #pragma unroll
      for (int ci = 0; ci < 2; ++ci) {
        int c = cg * 2 + ci;
        float4 x4 = *(const float4*)(inputs + ((size_t)bb * 128 + ccB * 8 + c) * 32768 + sp);
        atomicAdd(&acc[k0 * 9 + c], x4.x);
        atomicAdd(&acc[k1 * 9 + c], x4.y);
        atomicAdd(&acc[k2 * 9 + c], x4.z);
        atomicAdd(&acc[k3 * 9 + c], x4.w);
      }
      if (ccB == 0 && cg == 0) {
        atomicAdd(&cnts[k0], 1.f); atomicAdd(&cnts[k1], 1.f);
        atomicAdd(&cnts[k2], 1.f); atomicAdd(&cnts[k3], 1.f);
      }
    }
    __syncthreads();
    for (int m = t; m < 512 * 8; m += 256) {
      int k = m >> 3, c = m & 7;
      partial[(size_t)s * 65536 + k * 128 + ccB * 8 + c] = acc[k * 9 + c];
    }
    if (ccB == 0) for (int m = t; m < 512; m += 256) cpart[s * 512 + m] = cnts[m];
  } else {
    // ---- gather: 256 rows per block in 4 rounds of 64 ----
    float* eq = sh;             // [c][s] 128 x 64
    for (int rd = 0; rd < 4; ++rd) {
      const int n0 = (bid - 512) * 256 + rd * 64;
      const int b  = n0 >> 15;
      const int s0 = n0 & 32767;
      __syncthreads();
      {
        const int r  = t >> 2;
        const int qq = t & 3;
        const int kidx = (int)idxws[n0 + r];
        const float* src = emb + (size_t)kidx * 128;
        #pragma unroll
        for (int i = 0; i < 8; ++i) {
          int g = qq + 4 * i;
          float4 v = *(const float4*)(src + g * 4);
          float* dst = &eq[(g * 4) * 64 + r];
          dst[0] = v.x; dst[64] = v.y; dst[128] = v.z; dst[192] = v.w;
        }
      }
      __syncthreads();
      {
        const int sl = (t & 15) * 4;
        const int cb = t >> 4;
        #pragma unroll
        for (int j = 0; j < 8; ++j) {
          int c = cb + 16 * j;
          float4 v = *(const float4*)&eq[c * 64 + sl];
          *(float4*)(out + ((size_t)b * 128 + c) * 32768 + s0 + sl) = v;
        }
      }
    }
  }

  __threadfence();
  grid.sync();

  if (bid < 256) {
    // ---- fin ----
    float* cn   = sh;           // 512
    float* rsum = sh + 512;     // 256
    __syncthreads();
    float local = 0.f;
    for (int k = t; k < 512; k += 256) {
      float c = 0.f;
      for (int s = 0; s < NSPLIT; ++s) c += cpart[s * 512 + k];
      float v = 0.99f * ecs[k] + 0.01f * c;
      cn[k] = v; local += v;
    }
    rsum[t] = local;
    __syncthreads();
    for (int o = 128; o; o >>= 1) {
      if (t < o) rsum[t] += rsum[t + o];
      __syncthreads();
    }
    const float ntot = rsum[0];
    if (bid == 0) {
      for (int k = t; k < 512; k += 256) out[NCS_OFF + k] = cn[k];
      if (t == 0)
        out[LOSS_OFF] = 0.25f * sums[0] / 8388608.f - 0.01f * sums[1] / 65536.f;
    }
    const int i = bid * 256 + t;
    float dwv = 0.f;
    for (int s = 0; s < NSPLIT; ++s) dwv += partial[(size_t)s * 65536 + i];
    float val = 0.99f * emaw[i] + 0.01f * dwv;
    const int k = i >> 7;
    float sm = (cn[k] + 1e-5f) / (ntot + 0.00512f) * ntot;
    out[EMAW_OFF + i] = val;
    out[EMB_OFF + i] = val / sm;
  }
}

// ---------- fallback tail (ws too small): partials alias d_out, 3 kernels ----------
__global__ __launch_bounds__(256) void scatter_kernel(
    const float* __restrict__ inputs, const float* __restrict__ idxws,
    float* partial, float* __restrict__ cpart)
{
  __shared__ float acc[512 * 9];
  __shared__ float cnts[512];
  const int t = threadIdx.x;
  const int s = blockIdx.x >> 4, ccB = blockIdx.x & 15;
  const int R = 65536 / NSPLIT;
  for (int m = t; m < 512 * 9; m += 256) acc[m] = 0.f;
  if (ccB == 0) for (int m = t; m < 512; m += 256) cnts[m] = 0.f;
  __syncthreads();
  const int l = t & 63, cg = t >> 6;
  for (int it = 0; it < R / 256; ++it) {
    int n = s * R + it * 256;
    int bb = n >> 15;
    int sp = (n & 32767) + 4 * l;
    float4 i4 = *(const float4*)(idxws + n + 4 * l);
    int k0 = (int)i4.x, k1 = (int)i4.y, k2 = (int)i4.z, k3 = (int)i4.w;
    #pragma unroll
    for (int ci = 0; ci < 2; ++ci) {
      int c = cg * 2 + ci;
      float4 x4 = *(const float4*)(inputs + ((size_t)bb * 128 + ccB * 8 + c) * 32768 + sp);
      atomicAdd(&acc[k0 * 9 + c], x4.x);
      atomicAdd(&acc[k1 * 9 + c], x4.y);
      atomicAdd(&acc[k2 * 9 + c], x4.z);
      atomicAdd(&acc[k3 * 9 + c], x4.w);
    }
    if (ccB == 0 && cg == 0) {
      atomicAdd(&cnts[k0], 1.f); atomicAdd(&cnts[k1], 1.f);
      atomicAdd(&cnts[k2], 1.f); atomicAdd(&cnts[k3], 1.f);
    }
  }
  __syncthreads();
  for (int m = t; m < 512 * 8; m += 256) {
    int k = m >> 3, c = m & 7;
    partial[(size_t)s * 65536 + k * 128 + ccB * 8 + c] = acc[k * 9 + c];
  }
  if (ccB == 0) for (int m = t; m < 512; m += 256) cpart[s * 512 + m] = cnts[m];
}

__global__ __launch_bounds__(256) void fin_kernel(const float* __restrict__ ecs,
    const float* __restrict__ emaw, const float* partial,
    const float* __restrict__ cpart, const float* __restrict__ sums,
    float* out)
{
  __shared__ float cn[512];
  __shared__ float rsum[256];
  const int t = threadIdx.x;
  float local = 0.f;
  for (int k = t; k < 512; k += 256) {
    float c = 0.f;
    for (int s = 0; s < NSPLIT; ++s) c += cpart[s * 512 + k];
    float v = 0.99f * ecs[k] + 0.01f * c;
    cn[k] = v; local += v;
  }
  rsum[t] = local;
  __syncthreads();
  for (int o = 128; o; o >>= 1) {
    if (t < o) rsum[t] += rsum[t + o];
    __syncthreads();
  }
  const float ntot = rsum[0];
  if (blockIdx.x == 0) {
    for (int k = t; k < 512; k += 256) out[NCS_OFF + k] = cn[k];
    if (t == 0)
      out[LOSS_OFF] = 0.25f * sums[0] / 8388608.f - 0.01f * sums[1] / 65536.f;
  }
  const int i = blockIdx.x * 256 + t;
  float dwv = 0.f;
  for (int s = 0; s < NSPLIT; ++s) dwv += partial[(size_t)s * 65536 + i];
  float val = 0.99f * emaw[i] + 0.01f * dwv;
  const int k = i >> 7;
  float sm = (cn[k] + 1e-5f) / (ntot + 0.00512f) * ntot;
  out[EMAW_OFF + i] = val;
  out[EMB_OFF + i] = val / sm;
}

__global__ __launch_bounds__(256) void gather_kernel(const float* __restrict__ emb,
    const float* __restrict__ idxws, float* __restrict__ out)
{
  __shared__ float eq[128 * 64];
  const int t  = threadIdx.x;
  const int n0 = blockIdx.x * 64;
  const int b  = n0 >> 15;
  const int s0 = n0 & 32767;
  {
    const int r  = t >> 2;
    const int qq = t & 3;
    const int kidx = (int)idxws[n0 + r];
    const float* src = emb + (size_t)kidx * 128;
    #pragma unroll
    for (int i = 0; i < 8; ++i) {
      int g = qq + 4 * i;
      float4 v = *(const float4*)(src + g * 4);
      float* dst = &eq[(g * 4) * 64 + r];
      dst[0] = v.x; dst[64] = v.y; dst[128] = v.z; dst[192] = v.w;
    }
  }
  __syncthreads();
  {
    const int sl = (t & 15) * 4;
    const int cb = t >> 4;
    #pragma unroll
    for (int j = 0; j < 8; ++j) {
      int c = cb + 16 * j;
      float4 v = *(const float4*)&eq[c * 64 + sl];
      *(float4*)(out + ((size_t)b * 128 + c) * 32768 + s0 + sl) = v;
    }
  }
}

extern "C" void kernel_launch(void* const* d_in, const int* in_sizes, int n_in,
                              void* d_out, int out_size, void* d_ws, size_t ws_size,
                              hipStream_t stream) {
  const float* inputs = (const float*)d_in[0];
  const float* emb    = (const float*)d_in[1];
  const float* ecs    = (const float*)d_in[2];
  const float* emaw   = (const float*)d_in[3];
  float* out = (float*)d_out;
  float* wsf = (float*)d_ws;
  (void)in_sizes; (void)n_in; (void)out_size;

  // ws layout (floats): idxws 65536 | sums 16 | eeg 512 | ehig 16384 | elog 16384
  //                     | cpart 16384 | partial NSPLIT*65536
  float* idxws = wsf;
  float* sums  = wsf + 65536;
  float* eeg   = wsf + 65552;
  unsigned short* ehig = (unsigned short*)(wsf + 66064);
  unsigned short* elog = ehig + 65536;
  float* cpart = (float*)(elog + 65536);
  float* partial = cpart + 16384;
  const size_t need = ((size_t)(partial - wsf) + (size_t)NSPLIT * 65536) * 4;
  const bool big = ws_size >= need;

  hipMemsetAsync(sums, 0, 16 * sizeof(float), stream);
  prep_kernel<<<256,  256, 0, stream>>>(emb, ehig, elog, eeg);
  dist_kernel<<<1024, 256, 0, stream>>>(inputs, ehig, elog, eeg, out, idxws, sums);

  if (big) {
    void* kargs[] = { (void*)&inputs, (void*)&idxws, (void*)&partial,
                      (void*)&cpart, (void*)&ecs, (void*)&emaw,
                      (void*)&sums, (void*)&emb, (void*)&out };
    hipLaunchCooperativeKernel((const void*)coop_kernel, dim3(768), dim3(256),
                               kargs, 0, stream);
  } else {
    float* pout = out;   // partials alias quantized region; gather runs last
    scatter_kernel<<<16 * NSPLIT, 256, 0, stream>>>(inputs, idxws, pout, cpart);
    fin_kernel    <<<256,         256, 0, stream>>>(ecs, emaw, pout, cpart, sums, out);
    gather_kernel <<<1024,        256, 0, stream>>>(emb, idxws, out);
  }
}